// Round 5
// baseline (429.312 us; speedup 1.0000x reference)
//
#include <hip/hip_runtime.h>
#include <stdint.h>

// Correlation_29609504538974: 6-level spatial correlation, patch 3x3 + leaky_relu(corr/C).
// out_l[b, t, y, x] = leaky( (1/C) * sum_c f1[b,c,y,x] * f2[b,c,y+di,x+dj] ),
//   t=(di+1)*3+(dj+1); f1 = x_l, f2 = x_pre_l. Zero pad outside.
//
// R9 == R8 resubmitted (R8 bench failed with "container failed twice" -- infra
// acquire failure, no kernel verdict; full re-audit of bounds/barriers/shuffle
// masking found no fault vector).
//
// R8 theory: R7 showed the bottleneck is ISSUED vector-load bytes per CU:
// 16 B/px-ch issued (f1 8B/2px + 3 f2 row-taps x 8B/2px) = 844 MB through a
// ~10.2 B/cy/CU delivery pipe (m13 streaming ceiling); we ran at 9.3 B/cy/CU
// (91%). VALUBusy 10.7%, conflicts 0, HBM 25% -- only fewer issued bytes helps.
// Change: each lane owns a 2x2 PIXEL QUAD. 4 staged f2 rows (y0-1..y0+2) serve
// both output rows' taps; f1 is 2 rows: (4+2) float2 loads per 4 px = 12 B/px,
// a 25% issued-byte cut (844 -> 633 MB). Kept: 8-wave channel split + LDS
// reduce (two 128-px half-phases, LDS stays 36 KB), depth-2 pipeline,
// ws partials + fin, shuffle dj=+-1 taps (garbage only feeds store-masked taps).
// Chunks adapt to ws_size: x2 (14.9 MB, 1612 blocks) -> x1 (7.4 MB proven,
// 806 blocks) -> in-place fallback.

struct Lv {
  const float* f1;
  const float* f2;
  float* dst;        // partial base (ws region, or out region in fallback)
  int C, ss, csize;  // channels, log2(S), channels per wave
  uint32_t tiles;    // quad tiles (nquads/64, ceil)
  uint32_t nquads;   // npix/4
  uint32_t blk_end;  // cumulative block count
};
struct P { Lv lv[6]; };

struct Fv {
  const float* src;
  uint32_t end;      // cumulative out element end
  uint32_t cstride;  // 9*npix
  uint32_t nchunk;
  int ss;
  float invC;
};
struct PF { Fv f[6]; uint32_t total; };

#define LOADIT(A0, A1, R0, R1, R2, R3)   \
  do {                                   \
    (A0) = *(const float2*)(f1b + o1);   \
    (A1) = *(const float2*)(f1b + o2);   \
    (R0) = *(const float2*)(f2b + o0);   \
    (R1) = *(const float2*)(f2b + o1);   \
    (R2) = *(const float2*)(f2b + o2);   \
    (R3) = *(const float2*)(f2b + o3);   \
    f1b += S2;                           \
    f2b += S2;                           \
  } while (0)

// prev lane's .y == f2[x0-1]; next lane's .x == f2[x0+2]. All shuffle garbage
// (row/image/tile edges, clamped tail lanes) only feeds taps masked in corr_fin:
// lane layout guarantees x0==0 at every shfl_up discontinuity and x0==S-2 at
// every shfl_down discontinuity (qpi and tile sizes are multiples of quads/row).
#define FMAIT(A0, A1, R0, R1, R2, R3)                              \
  do {                                                             \
    const float2 rr_[4] = {R0, R1, R2, R3};                        \
    float pw_[4], nx_[4];                                          \
    _Pragma("unroll") for (int m_ = 0; m_ < 4; ++m_) {             \
      pw_[m_] = __shfl_up(rr_[m_].y, 1);                           \
      nx_[m_] = __shfl_down(rr_[m_].x, 1);                         \
    }                                                              \
    _Pragma("unroll") for (int r_ = 0; r_ < 2; ++r_) {             \
      const float2 a_ = r_ ? (A1) : (A0);                          \
      _Pragma("unroll") for (int d_ = 0; d_ < 3; ++d_) {           \
        const float2 R_ = rr_[r_ + d_];                            \
        const float p_ = pw_[r_ + d_], n_ = nx_[r_ + d_];          \
        acc[r_][d_][0][0] = fmaf(a_.x, p_, acc[r_][d_][0][0]);     \
        acc[r_][d_][0][1] = fmaf(a_.y, R_.x, acc[r_][d_][0][1]);   \
        acc[r_][d_][1][0] = fmaf(a_.x, R_.x, acc[r_][d_][1][0]);   \
        acc[r_][d_][1][1] = fmaf(a_.y, R_.y, acc[r_][d_][1][1]);   \
        acc[r_][d_][2][0] = fmaf(a_.x, R_.y, acc[r_][d_][2][0]);   \
        acc[r_][d_][2][1] = fmaf(a_.y, n_, acc[r_][d_][2][1]);     \
      }                                                            \
    }                                                              \
  } while (0)

__global__ __launch_bounds__(512, 6) void corr_part(P p) {
  __shared__ float red[8][9 * 128];  // 36 KB

  const uint32_t bid = blockIdx.x;
  int l = 0;
#pragma unroll
  for (int i = 0; i < 5; ++i) l += (bid >= p.lv[i].blk_end) ? 1 : 0;
  const Lv L = p.lv[l];
  const uint32_t local = bid - (l ? p.lv[l - 1].blk_end : 0u);
  const uint32_t chunk = local / L.tiles;  // chunk-major: tile-neighbors adjacent
  const uint32_t tile = local - chunk * L.tiles;

  const int w = (int)(threadIdx.x >> 6);
  const int lane = (int)(threadIdx.x & 63u);
  const int ss = L.ss;
  const int S = 1 << ss;
  const int S2 = 1 << (2 * ss);
  const uint32_t qpiM = (1u << (2 * ss - 2)) - 1u;  // quads-per-image - 1
  const uint32_t qrwM = (1u << (ss - 1)) - 1u;      // quads-per-row - 1

  uint32_t g = tile * 64u + (uint32_t)lane;  // global quad id
  if (g >= L.nquads) g = L.nquads - 1u;      // tail lanes: garbage, stores masked
  const uint32_t b = g >> (2 * ss - 2);
  const uint32_t qyx = g & qpiM;
  const int y0 = (int)((qyx >> (ss - 1)) << 1);

  const uint32_t c0 = chunk * (uint32_t)(8 * L.csize) + (uint32_t)(w * L.csize);
  const size_t pbase = ((size_t)(b * (uint32_t)L.C + c0)) << (2 * ss);
  const float* __restrict__ f1b = L.f1 + pbase;
  const float* __restrict__ f2b = L.f2 + pbase;

  const int ym = (y0 - 1) < 0 ? 0 : (y0 - 1);          // clamped; taps masked in fin
  const int yp = (y0 + 2) > (S - 1) ? (S - 1) : (y0 + 2);
  const int xb = (int)((qyx & qrwM) << 1);
  const int o0 = ym * S + xb;
  const int o1 = y0 * S + xb;
  const int o2 = o1 + S;        // y0+1 always < S
  const int o3 = yp * S + xb;

  float acc[2][3][3][2];  // [outrow][rowtap][coltap][e]
#pragma unroll
  for (int r = 0; r < 2; ++r)
#pragma unroll
    for (int d = 0; d < 3; ++d)
#pragma unroll
      for (int dd = 0; dd < 3; ++dd) {
        acc[r][d][dd][0] = 0.f;
        acc[r][d][dd][1] = 0.f;
      }

  // Depth-2 software pipeline over n channel-iterations (n even, >= 2).
  const int n = L.csize;
  float2 a00, a01, u0, v0, w0, z0;
  float2 a10, a11, u1, v1, w1, z1;
  LOADIT(a00, a01, u0, v0, w0, z0);
#pragma unroll 1
  for (int j = 0; j + 2 < n; j += 2) {
    LOADIT(a10, a11, u1, v1, w1, z1);
    FMAIT(a00, a01, u0, v0, w0, z0);
    LOADIT(a00, a01, u0, v0, w0, z0);
    FMAIT(a10, a11, u1, v1, w1, z1);
  }
  LOADIT(a10, a11, u1, v1, w1, z1);
  FMAIT(a00, a01, u0, v0, w0, z0);
  FMAIT(a10, a11, u1, v1, w1, z1);

  // Two half-phases: lanes 0..31's quads (128 px), then lanes 32..63's.
  float* dbase = L.dst + (size_t)chunk * 9u * ((size_t)L.nquads << 2);
#pragma unroll
  for (int h = 0; h < 2; ++h) {
    if ((lane >> 5) == h) {
      const int q = lane & 31;
#pragma unroll
      for (int r = 0; r < 2; ++r)
#pragma unroll
        for (int d = 0; d < 3; ++d)
#pragma unroll
          for (int dd = 0; dd < 3; ++dd) {
            const int t = d * 3 + dd;
            *(float2*)&red[w][t * 128 + q * 4 + r * 2] =
                make_float2(acc[r][d][dd][0], acc[r][d][dd][1]);
          }
    }
    __syncthreads();
    for (int idx = (int)threadIdx.x; idx < 9 * 128; idx += 512) {
      float s = 0.f;
#pragma unroll
      for (int ww = 0; ww < 8; ++ww) s += red[ww][idx];
      const int t = idx >> 7;
      const int pl = idx & 127;
      const uint32_t g2 = tile * 64u + (uint32_t)(h * 32) + (uint32_t)(pl >> 2);
      if (g2 < L.nquads) {
        const int k = pl & 3;
        const uint32_t b2 = g2 >> (2 * ss - 2);
        const uint32_t qyx2 = g2 & qpiM;
        const int yy = (int)((qyx2 >> (ss - 1)) << 1) + (k >> 1);
        const int xx = (int)((qyx2 & qrwM) << 1) + (k & 1);
        dbase[(((size_t)(b2 * 9u + (uint32_t)t)) << (2 * ss)) +
              (uint32_t)(yy * S + xx)] = s;
      }
    }
    __syncthreads();
  }
}

__global__ __launch_bounds__(256) void corr_fin(PF p, float* __restrict__ out) {
  const uint32_t e = blockIdx.x * 256u + threadIdx.x;
  if (e >= p.total) return;
  int l = 0;
#pragma unroll
  for (int i = 0; i < 5; ++i) l += (e >= p.f[i].end) ? 1 : 0;
  const Fv F = p.f[l];
  const int ss = F.ss;
  const int S = 1 << ss;
  const int S2 = 1 << (2 * ss);
  const uint32_t local = e - (F.end - F.cstride);
  const uint32_t bt = local >> (2 * ss);
  const uint32_t yx = local & (uint32_t)(S2 - 1);
  const uint32_t t = bt % 9u;  // constant div -> magic mul
  const int y = (int)(yx >> ss);
  const int x = (int)(yx & (uint32_t)(S - 1));
  const int di = (int)t / 3 - 1;
  const int dj = (int)t % 3 - 1;
  const int qy = y + di;
  const int qx = x + dj;

  float s = 0.f;
  for (uint32_t k = 0; k < F.nchunk; ++k) s += F.src[(size_t)k * F.cstride + local];

  float v = 0.f;
  if ((qy >= 0) & (qy < S) & (qx >= 0) & (qx < S)) {
    v = s * F.invC;
    v = v >= 0.f ? v : 0.01f * v;
  }
  out[e] = v;
}

extern "C" void kernel_launch(void* const* d_in, const int* in_sizes, int n_in,
                              void* d_out, int out_size, void* d_ws, size_t ws_size,
                              hipStream_t stream) {
  static const int CH[6] = {512, 1024, 512, 256, 256, 256};
  static const int LG[6] = {6, 5, 4, 3, 2, 1};
  static const int BASE[6] = {2, 4, 2, 1, 1, 1};  // chunk base (7.4 MB, R7-proven)

  // setup_inputs() dict order is interleaved: d_in[2i]=x_pre_i, d_in[2i+1]=x_i.
  const bool interleaved = (n_in >= 2) && (in_sizes[0] == in_sizes[1]);

  uint32_t npixs[6], ooff[6], oacc = 0;
  for (int i = 0; i < 6; ++i) {
    npixs[i] = 16u << (2 * LG[i]);
    ooff[i] = oacc;
    oacc += 9u * npixs[i];
  }

  // Adaptive chunk multiplier: m=2 (1612 blocks) if ws fits, else m=1 (806,
  // proven), else fallback chunk=1 writing raw sums into out (fin in-place).
  size_t need1 = 0;
  for (int i = 0; i < 6; ++i) need1 += (size_t)BASE[i] * 9u * npixs[i];
  need1 *= sizeof(float);
  const size_t need2 = need1 * 2u;
  int mode;  // 2, 1, or 0 (fallback)
  if (d_ws && ws_size >= need2) mode = 2;
  else if (d_ws && ws_size >= need1) mode = 1;
  else mode = 0;

  int NCK[6];
  for (int i = 0; i < 6; ++i) NCK[i] = (mode == 0) ? 1 : BASE[i] * mode;

  P p;
  PF pf;
  float* ws = (float*)d_ws;
  float* out = (float*)d_out;
  uint32_t bend = 0;
  size_t woff = 0;
  for (int i = 0; i < 6; ++i) {
    const uint32_t nquads = npixs[i] >> 2;
    const uint32_t tiles = (nquads + 63u) / 64u;
    Lv& L = p.lv[i];
    L.f1 = (const float*)d_in[interleaved ? (2 * i + 1) : (6 + i)];
    L.f2 = (const float*)d_in[interleaved ? (2 * i) : i];
    L.dst = (mode == 0) ? (out + ooff[i]) : (ws + woff);
    L.C = CH[i];
    L.ss = LG[i];
    L.csize = CH[i] / (8 * NCK[i]);
    L.tiles = tiles;
    L.nquads = nquads;
    bend += tiles * (uint32_t)NCK[i];
    L.blk_end = bend;

    Fv& F = pf.f[i];
    F.src = L.dst;
    F.end = ooff[i] + 9u * npixs[i];
    F.cstride = 9u * npixs[i];
    F.nchunk = (uint32_t)NCK[i];
    F.ss = LG[i];
    F.invC = 1.0f / (float)CH[i];
    woff += (size_t)NCK[i] * 9u * npixs[i];
  }
  pf.total = oacc;

  corr_part<<<bend, 512, 0, stream>>>(p);
  corr_fin<<<(oacc + 255u) / 256u, 256, 0, stream>>>(pf, out);
}

// Round 6
// 399.130 us; speedup vs baseline: 1.0756x; 1.0756x over previous
//
#include <hip/hip_runtime.h>
#include <stdint.h>

// Correlation_29609504538974: 6-level spatial correlation, patch 3x3 + leaky_relu(corr/C).
// out_l[b, t, y, x] = leaky( (1/C) * sum_c f1[b,c,y,x] * f2[b,c,y+di,x+dj] ),
//   t=(di+1)*3+(dj+1); f1 = x_l, f2 = x_pre_l. Zero pad outside.
//
// R10: R9 (quad layout, launch_bounds(512,6)) SPILLED: VGPR cap 84 < ~100 needed.
// Signature: WRITE_SIZE 95 MB vs 14.9 MB true partials (= ~1.6 spilled dwords
// reloaded per channel-iter to scratch->HBM), FETCH +25 MB, time 148->173 us.
// Fix: __launch_bounds__(512, 4) -> VGPR cap 128, no spill; occupancy ~50%
// (2 blocks/CU). This is the clean test of the R8 issued-byte theory:
// quad layout = 12 B/px-ch issued (f1 2 rows + 4 staged f2 rows per 2x2 quad)
// vs R7's 16 B/px-ch. Issue rate is weakly occupancy-dependent (R6: 8.3 B/cy/CU
// @50%, R7: 9.3 @60%) -> predict corr_part ~115-130 us.
// Kept: 8-wave channel split + LDS reduce (two 128-px half-phases, 36 KB),
// depth-2 software pipeline, ws partials + fin, shuffle dj=+-1 taps (all
// shuffle garbage lands only in store-masked taps). Chunks adapt to ws_size.

struct Lv {
  const float* f1;
  const float* f2;
  float* dst;        // partial base (ws region, or out region in fallback)
  int C, ss, csize;  // channels, log2(S), channels per wave
  uint32_t tiles;    // quad tiles (nquads/64, ceil)
  uint32_t nquads;   // npix/4
  uint32_t blk_end;  // cumulative block count
};
struct P { Lv lv[6]; };

struct Fv {
  const float* src;
  uint32_t end;      // cumulative out element end
  uint32_t cstride;  // 9*npix
  uint32_t nchunk;
  int ss;
  float invC;
};
struct PF { Fv f[6]; uint32_t total; };

#define LOADIT(A0, A1, R0, R1, R2, R3)   \
  do {                                   \
    (A0) = *(const float2*)(f1b + o1);   \
    (A1) = *(const float2*)(f1b + o2);   \
    (R0) = *(const float2*)(f2b + o0);   \
    (R1) = *(const float2*)(f2b + o1);   \
    (R2) = *(const float2*)(f2b + o2);   \
    (R3) = *(const float2*)(f2b + o3);   \
    f1b += S2;                           \
    f2b += S2;                           \
  } while (0)

// prev lane's .y == f2[x0-1]; next lane's .x == f2[x0+2]. All shuffle garbage
// (row/image/tile edges, clamped tail lanes) only feeds taps masked in corr_fin:
// lane layout guarantees x0==0 at every shfl_up discontinuity and x0==S-2 at
// every shfl_down discontinuity (qpi and tile sizes are multiples of quads/row).
#define FMAIT(A0, A1, R0, R1, R2, R3)                              \
  do {                                                             \
    const float2 rr_[4] = {R0, R1, R2, R3};                        \
    float pw_[4], nx_[4];                                          \
    _Pragma("unroll") for (int m_ = 0; m_ < 4; ++m_) {             \
      pw_[m_] = __shfl_up(rr_[m_].y, 1);                           \
      nx_[m_] = __shfl_down(rr_[m_].x, 1);                         \
    }                                                              \
    _Pragma("unroll") for (int r_ = 0; r_ < 2; ++r_) {             \
      const float2 a_ = r_ ? (A1) : (A0);                          \
      _Pragma("unroll") for (int d_ = 0; d_ < 3; ++d_) {           \
        const float2 R_ = rr_[r_ + d_];                            \
        const float p_ = pw_[r_ + d_], n_ = nx_[r_ + d_];          \
        acc[r_][d_][0][0] = fmaf(a_.x, p_, acc[r_][d_][0][0]);     \
        acc[r_][d_][0][1] = fmaf(a_.y, R_.x, acc[r_][d_][0][1]);   \
        acc[r_][d_][1][0] = fmaf(a_.x, R_.x, acc[r_][d_][1][0]);   \
        acc[r_][d_][1][1] = fmaf(a_.y, R_.y, acc[r_][d_][1][1]);   \
        acc[r_][d_][2][0] = fmaf(a_.x, R_.y, acc[r_][d_][2][0]);   \
        acc[r_][d_][2][1] = fmaf(a_.y, n_, acc[r_][d_][2][1]);     \
      }                                                            \
    }                                                              \
  } while (0)

__global__ __launch_bounds__(512, 4) void corr_part(P p) {
  __shared__ float red[8][9 * 128];  // 36 KB

  const uint32_t bid = blockIdx.x;
  int l = 0;
#pragma unroll
  for (int i = 0; i < 5; ++i) l += (bid >= p.lv[i].blk_end) ? 1 : 0;
  const Lv L = p.lv[l];
  const uint32_t local = bid - (l ? p.lv[l - 1].blk_end : 0u);
  const uint32_t chunk = local / L.tiles;  // chunk-major: tile-neighbors adjacent
  const uint32_t tile = local - chunk * L.tiles;

  const int w = (int)(threadIdx.x >> 6);
  const int lane = (int)(threadIdx.x & 63u);
  const int ss = L.ss;
  const int S = 1 << ss;
  const int S2 = 1 << (2 * ss);
  const uint32_t qpiM = (1u << (2 * ss - 2)) - 1u;  // quads-per-image - 1
  const uint32_t qrwM = (1u << (ss - 1)) - 1u;      // quads-per-row - 1

  uint32_t g = tile * 64u + (uint32_t)lane;  // global quad id
  if (g >= L.nquads) g = L.nquads - 1u;      // tail lanes: garbage, stores masked
  const uint32_t b = g >> (2 * ss - 2);
  const uint32_t qyx = g & qpiM;
  const int y0 = (int)((qyx >> (ss - 1)) << 1);

  const uint32_t c0 = chunk * (uint32_t)(8 * L.csize) + (uint32_t)(w * L.csize);
  const size_t pbase = ((size_t)(b * (uint32_t)L.C + c0)) << (2 * ss);
  const float* __restrict__ f1b = L.f1 + pbase;
  const float* __restrict__ f2b = L.f2 + pbase;

  const int ym = (y0 - 1) < 0 ? 0 : (y0 - 1);          // clamped; taps masked in fin
  const int yp = (y0 + 2) > (S - 1) ? (S - 1) : (y0 + 2);
  const int xb = (int)((qyx & qrwM) << 1);
  const int o0 = ym * S + xb;
  const int o1 = y0 * S + xb;
  const int o2 = o1 + S;        // y0+1 always < S
  const int o3 = yp * S + xb;

  float acc[2][3][3][2];  // [outrow][rowtap][coltap][e]
#pragma unroll
  for (int r = 0; r < 2; ++r)
#pragma unroll
    for (int d = 0; d < 3; ++d)
#pragma unroll
      for (int dd = 0; dd < 3; ++dd) {
        acc[r][d][dd][0] = 0.f;
        acc[r][d][dd][1] = 0.f;
      }

  // Depth-2 software pipeline over n channel-iterations (n even, >= 2).
  const int n = L.csize;
  float2 a00, a01, u0, v0, w0, z0;
  float2 a10, a11, u1, v1, w1, z1;
  LOADIT(a00, a01, u0, v0, w0, z0);
#pragma unroll 1
  for (int j = 0; j + 2 < n; j += 2) {
    LOADIT(a10, a11, u1, v1, w1, z1);
    FMAIT(a00, a01, u0, v0, w0, z0);
    LOADIT(a00, a01, u0, v0, w0, z0);
    FMAIT(a10, a11, u1, v1, w1, z1);
  }
  LOADIT(a10, a11, u1, v1, w1, z1);
  FMAIT(a00, a01, u0, v0, w0, z0);
  FMAIT(a10, a11, u1, v1, w1, z1);

  // Two half-phases: lanes 0..31's quads (128 px), then lanes 32..63's.
  float* dbase = L.dst + (size_t)chunk * 9u * ((size_t)L.nquads << 2);
#pragma unroll
  for (int h = 0; h < 2; ++h) {
    if ((lane >> 5) == h) {
      const int q = lane & 31;
#pragma unroll
      for (int r = 0; r < 2; ++r)
#pragma unroll
        for (int d = 0; d < 3; ++d)
#pragma unroll
          for (int dd = 0; dd < 3; ++dd) {
            const int t = d * 3 + dd;
            *(float2*)&red[w][t * 128 + q * 4 + r * 2] =
                make_float2(acc[r][d][dd][0], acc[r][d][dd][1]);
          }
    }
    __syncthreads();
    for (int idx = (int)threadIdx.x; idx < 9 * 128; idx += 512) {
      float s = 0.f;
#pragma unroll
      for (int ww = 0; ww < 8; ++ww) s += red[ww][idx];
      const int t = idx >> 7;
      const int pl = idx & 127;
      const uint32_t g2 = tile * 64u + (uint32_t)(h * 32) + (uint32_t)(pl >> 2);
      if (g2 < L.nquads) {
        const int k = pl & 3;
        const uint32_t b2 = g2 >> (2 * ss - 2);
        const uint32_t qyx2 = g2 & qpiM;
        const int yy = (int)((qyx2 >> (ss - 1)) << 1) + (k >> 1);
        const int xx = (int)((qyx2 & qrwM) << 1) + (k & 1);
        dbase[(((size_t)(b2 * 9u + (uint32_t)t)) << (2 * ss)) +
              (uint32_t)(yy * S + xx)] = s;
      }
    }
    __syncthreads();
  }
}

__global__ __launch_bounds__(256) void corr_fin(PF p, float* __restrict__ out) {
  const uint32_t e = blockIdx.x * 256u + threadIdx.x;
  if (e >= p.total) return;
  int l = 0;
#pragma unroll
  for (int i = 0; i < 5; ++i) l += (e >= p.f[i].end) ? 1 : 0;
  const Fv F = p.f[l];
  const int ss = F.ss;
  const int S = 1 << ss;
  const int S2 = 1 << (2 * ss);
  const uint32_t local = e - (F.end - F.cstride);
  const uint32_t bt = local >> (2 * ss);
  const uint32_t yx = local & (uint32_t)(S2 - 1);
  const uint32_t t = bt % 9u;  // constant div -> magic mul
  const int y = (int)(yx >> ss);
  const int x = (int)(yx & (uint32_t)(S - 1));
  const int di = (int)t / 3 - 1;
  const int dj = (int)t % 3 - 1;
  const int qy = y + di;
  const int qx = x + dj;

  float s = 0.f;
  for (uint32_t k = 0; k < F.nchunk; ++k) s += F.src[(size_t)k * F.cstride + local];

  float v = 0.f;
  if ((qy >= 0) & (qy < S) & (qx >= 0) & (qx < S)) {
    v = s * F.invC;
    v = v >= 0.f ? v : 0.01f * v;
  }
  out[e] = v;
}

extern "C" void kernel_launch(void* const* d_in, const int* in_sizes, int n_in,
                              void* d_out, int out_size, void* d_ws, size_t ws_size,
                              hipStream_t stream) {
  static const int CH[6] = {512, 1024, 512, 256, 256, 256};
  static const int LG[6] = {6, 5, 4, 3, 2, 1};
  static const int BASE[6] = {2, 4, 2, 1, 1, 1};  // chunk base (7.4 MB)

  // setup_inputs() dict order is interleaved: d_in[2i]=x_pre_i, d_in[2i+1]=x_i.
  const bool interleaved = (n_in >= 2) && (in_sizes[0] == in_sizes[1]);

  uint32_t npixs[6], ooff[6], oacc = 0;
  for (int i = 0; i < 6; ++i) {
    npixs[i] = 16u << (2 * LG[i]);
    ooff[i] = oacc;
    oacc += 9u * npixs[i];
  }

  // Adaptive chunk multiplier: m=2 (1612 blocks) if ws fits, else m=1 (806),
  // else fallback chunk=1 writing raw sums into out (fin in-place).
  size_t need1 = 0;
  for (int i = 0; i < 6; ++i) need1 += (size_t)BASE[i] * 9u * npixs[i];
  need1 *= sizeof(float);
  const size_t need2 = need1 * 2u;
  int mode;  // 2, 1, or 0 (fallback)
  if (d_ws && ws_size >= need2) mode = 2;
  else if (d_ws && ws_size >= need1) mode = 1;
  else mode = 0;

  int NCK[6];
  for (int i = 0; i < 6; ++i) NCK[i] = (mode == 0) ? 1 : BASE[i] * mode;

  P p;
  PF pf;
  float* ws = (float*)d_ws;
  float* out = (float*)d_out;
  uint32_t bend = 0;
  size_t woff = 0;
  for (int i = 0; i < 6; ++i) {
    const uint32_t nquads = npixs[i] >> 2;
    const uint32_t tiles = (nquads + 63u) / 64u;
    Lv& L = p.lv[i];
    L.f1 = (const float*)d_in[interleaved ? (2 * i + 1) : (6 + i)];
    L.f2 = (const float*)d_in[interleaved ? (2 * i) : i];
    L.dst = (mode == 0) ? (out + ooff[i]) : (ws + woff);
    L.C = CH[i];
    L.ss = LG[i];
    L.csize = CH[i] / (8 * NCK[i]);
    L.tiles = tiles;
    L.nquads = nquads;
    bend += tiles * (uint32_t)NCK[i];
    L.blk_end = bend;

    Fv& F = pf.f[i];
    F.src = L.dst;
    F.end = ooff[i] + 9u * npixs[i];
    F.cstride = 9u * npixs[i];
    F.nchunk = (uint32_t)NCK[i];
    F.ss = LG[i];
    F.invC = 1.0f / (float)CH[i];
    woff += (size_t)NCK[i] * 9u * npixs[i];
  }
  pf.total = oacc;

  corr_part<<<bend, 512, 0, stream>>>(p);
  corr_fin<<<(oacc + 255u) / 256u, 256, 0, stream>>>(pf, out);
}